// Round 14
// baseline (246.270 us; speedup 1.0000x reference)
//
#include <hip/hip_runtime.h>
#include <hip/hip_bf16.h>
#include <cstdint>
#include <cstddef>

// LSTM fused pipeline, round 14.
// Core: 128x128 tile, 256 thr / 4 waves (2x2), wave = 64x64 (4x4 frags),
// BK=32, dbuf 2x16KB = 32KB LDS -> 4 blocks/CU = 16 waves/CU, with
// slot^=row&3 XOR swizzle (both-sides: pre-swizzled gload source + swizzled
// ds_read; 8 lanes/4-bank-span = 2/bank = conflict-free) and counted
// vmcnt(4) schedule (never drains to 0 in-loop).
// LDS traffic 46 B/KFLOP (was 61) -> combo floor ~25 us.
// Epilogue: two 128x64 f32 halves (R8 scheme). Jobs/Gz1R/dispatches = R13.

typedef __bf16 bf16_t;
typedef __bf16 bf16x8 __attribute__((ext_vector_type(8)));
typedef __bf16 bf16x4 __attribute__((ext_vector_type(4)));
typedef float f32x4 __attribute__((ext_vector_type(4)));

__device__ __forceinline__ void gload_lds16(const bf16_t* g, bf16_t* l) {
    __builtin_amdgcn_global_load_lds(
        (const __attribute__((address_space(1))) void*)g,
        (__attribute__((address_space(3))) void*)l,
        16, 0, 0);
}

__device__ __forceinline__ float sigmoid_f(float x) {
    return 1.f / (1.f + __expf(-x));
}
__device__ __forceinline__ float tanh_fast(float x) {
    const float t = __expf(2.f * x);
    return 1.f - 2.f / (t + 1.f);
}

// mode 0: GEMM + LSTM cell epilogue (gate-interleaved cols j=4n+g).
// mode 1: GEMM + bias -> f32 C (ldc fixed 4096).
struct Job {
    const bf16_t* A;       // [1024][lda]
    const bf16_t* B;       // [N][ldb], K<=ldb
    const float*  add;     // f32 [1024][4096] or null
    const float*  bias;    // f32 or null
    float*        c;       // f32 [1024][1024] cell state         (mode 0)
    bf16_t*       h1;      // h dest 1                            (mode 0)
    bf16_t*       h2;      // h dest 2 or null                    (mode 0)
    float*        C;       // f32 out, ldc=4096                   (mode 1)
    int lda, ldb, K, h1s, h2s, mode;
};

// All jobs: M=1024 (8 row-tiles of 128). Flat job ranges [0,n0), [n0,n01), rest.
__global__ __launch_bounds__(256, 3) void fused_multi(Job j0, Job j1, Job j2, int n0, int n01)
{
    __shared__ __align__(16) char smem[32768];   // buf b: lsA b*16KB, lsB +8KB

    const int bid = blockIdx.x;
    Job ja; int local, n;
    if (bid < n0)        { ja = j0; local = bid;       n = n0; }
    else if (bid < n01)  { ja = j1; local = bid - n0;  n = n01 - n0; }
    else                 { ja = j2; local = bid - n01; n = (int)gridDim.x - n01; }

    // XCD-aware: bid%8 = XCD (job bases %8==0); x-major chunks per XCD so
    // same-B-panel tiles share an L2.
    const int q    = n >> 3;                          // n is a multiple of 8
    const int tile = (local & 7) * q + (local >> 3);
    const int bcol = (tile >> 3) * 128;
    const int brow = (tile & 7) * 128;

    const int tid  = threadIdx.x;
    const int lane = tid & 63;
    const int wave = tid >> 6;            // 0..3
    const int wm = (wave >> 1) * 64;
    const int wn = (wave & 1) * 64;

    // staging: lane l -> row ch*16 + (l>>2); stored slot (l&3) holds logical
    // slot (l&3)^((l>>2)&3)  => fetch that global slot (rule #21 both-sides).
    const int srow = lane >> 2;                                  // 0..15
    const int ssw  = (((lane & 3) ^ ((lane >> 2) & 3)) * 8);     // source col elems
    const int nkt  = ja.K >> 5;                                  // BK=32 steps

    const int fr = lane & 15;
    // read: logical slot = lane>>4, stored at slot ^ (row&3), row&3 == lane&3
    const int ko = (((lane >> 4) ^ (lane & 3)) * 8);

    f32x4 acc[4][4] = {};

    auto stage = [&](int buf, int ktel) {        // 4 gload_lds per wave
        bf16_t* lsA = (bf16_t*)(smem + buf * 16384);
        bf16_t* lsB = (bf16_t*)(smem + buf * 16384 + 8192);
#pragma unroll
        for (int it = 0; it < 2; ++it) {
            const int ch = wave * 2 + it;        // 0..7
            const int row = ch * 16 + srow;      // 0..127
            gload_lds16(ja.A + (size_t)(brow + row) * ja.lda + ktel + ssw, &lsA[ch * 512]);
            gload_lds16(ja.B + (size_t)(bcol + row) * ja.ldb + ktel + ssw, &lsB[ch * 512]);
        }
    };

    stage(0, 0);

    for (int kt = 0; kt < nkt; ++kt) {
        const int buf = kt & 1;
        if (kt + 1 < nkt) {
            stage(buf ^ 1, (kt + 1) << 5);       // prefetch: 4 more in flight
            asm volatile("s_waitcnt vmcnt(4)" ::: "memory");   // wait stage(kt) only
        } else {
            asm volatile("s_waitcnt vmcnt(0)" ::: "memory");   // final drain
        }
        __builtin_amdgcn_sched_barrier(0);
        __builtin_amdgcn_s_barrier();            // all waves' stage(kt) landed
        __builtin_amdgcn_sched_barrier(0);

        const bf16_t* lsA = (const bf16_t*)(smem + buf * 16384);
        const bf16_t* lsB = (const bf16_t*)(smem + buf * 16384 + 8192);
        bf16x8 af[4], bfv[4];
#pragma unroll
        for (int m = 0; m < 4; ++m)
            af[m] = *(const bf16x8*)&lsA[(wm + m * 16 + fr) * 32 + ko];
#pragma unroll
        for (int nn = 0; nn < 4; ++nn)
            bfv[nn] = *(const bf16x8*)&lsB[(wn + nn * 16 + fr) * 32 + ko];
#pragma unroll
        for (int m = 0; m < 4; ++m)
#pragma unroll
            for (int nn = 0; nn < 4; ++nn)
                acc[m][nn] = __builtin_amdgcn_mfma_f32_16x16x32_bf16(af[m], bfv[nn], acc[m][nn], 0, 0, 0);
        __builtin_amdgcn_sched_barrier(0);
        __builtin_amdgcn_s_barrier();            // WAR: next stage overwrites buf^1
    }

    // C/D layout: col = lane&15, row = (lane>>4)*4 + reg
    const int cr = (lane >> 4) * 4;
    const int cc = lane & 15;

    if (ja.mode == 1) {
#pragma unroll
        for (int nn = 0; nn < 4; ++nn) {
            const int col = bcol + wn + nn * 16 + cc;
            const float bv = ja.bias ? ja.bias[col] : 0.f;
#pragma unroll
            for (int m = 0; m < 4; ++m) {
                const int row0 = brow + wm + m * 16 + cr;
#pragma unroll
                for (int r = 0; r < 4; ++r)
                    ja.C[(size_t)(row0 + r) * 4096 + col] = acc[m][nn][r] + bv;
            }
        }
        return;
    }

    // mode 0: two 128x64 f32 halves through the 32KB LDS, then cell (R8 scheme)
    float* gsm = (float*)smem;
#pragma unroll
    for (int h = 0; h < 2; ++h) {
        if ((wave & 1) == h) {     // waves with wn == h*64 dump their acc
#pragma unroll
            for (int nn = 0; nn < 4; ++nn)
#pragma unroll
                for (int m = 0; m < 4; ++m)
#pragma unroll
                    for (int r = 0; r < 4; ++r) {
                        const int row = wm + m * 16 + cr + r;
                        const int col = nn * 16 + cc;
                        gsm[row * 64 + (col ^ (((row >> 2) & 1) << 4))] = acc[m][nn][r];
                    }
        }
        __syncthreads();
        // 128 rows x 16 n-quads = 2048 items, 8 per thread
#pragma unroll
        for (int p = 0; p < 8; ++p) {
            const int idx = p * 256 + tid;
            const int rl = idx >> 4;          // 0..127
            const int nn = idx & 15;          // 0..15
            float4 gv = *(const float4*)&gsm[rl * 64 + ((nn * 4) ^ (((rl >> 2) & 1) << 4))];
            const int grow = brow + rl;
            const int j0c = bcol + h * 64 + nn * 4;
            if (ja.add) {
                const float4 av = *(const float4*)&ja.add[(size_t)grow * 4096 + j0c];
                gv.x += av.x; gv.y += av.y; gv.z += av.z; gv.w += av.w;
            }
            if (ja.bias) {
                const float4 bv = *(const float4*)&ja.bias[j0c];
                gv.x += bv.x; gv.y += bv.y; gv.z += bv.z; gv.w += bv.w;
            }
            const int ng = j0c >> 2;          // global n
            const size_t ci = (size_t)grow * 1024 + ng;
            const float cn = sigmoid_f(gv.y) * ja.c[ci] + sigmoid_f(gv.x) * tanh_fast(gv.z);
            const float hh = sigmoid_f(gv.w) * tanh_fast(cn);
            ja.c[ci] = cn;
            const bf16_t hb = (bf16_t)hh;
            ja.h1[(size_t)grow * ja.h1s + ng] = hb;
            if (ja.h2) ja.h2[(size_t)grow * ja.h2s + ng] = hb;
        }
        __syncthreads();   // gsm reads done before next half overwrites
    }
}

// ---- merged prep: all weight conversions + reorders + init in ONE dispatch ----
__global__ __launch_bounds__(256) void prep_all(
    const float* __restrict__ z,
    const float4* __restrict__ Wih0, const float4* __restrict__ Whh0,
    const float4* __restrict__ Wih1, const float4* __restrict__ Whh1,
    const float4* __restrict__ Wlin,
    const float* __restrict__ bih0, const float* __restrict__ bhh0,
    const float* __restrict__ bih1, const float* __restrict__ bhh1,
    bf16x4* __restrict__ Wih0R, bf16x4* __restrict__ Whh0R, bf16x4* __restrict__ Wsum0R,
    bf16x4* __restrict__ WcatR1, bf16x4* __restrict__ Wlinb,
    bf16_t* __restrict__ zb, bf16_t* __restrict__ X0,
    float* __restrict__ c0, float* __restrict__ c1,
    float* __restrict__ b0R, float* __restrict__ b1R)
{
    const int t = blockIdx.x * 256 + threadIdx.x;
    if (t < 1048576) {
        const int j = t >> 8, col = t & 255;
        const int g = j & 3, nn = j >> 2;
        const int src = (g * 1024 + nn) * 256 + col;
        const float4 a = Wih0[src];
        const float4 b = Whh0[src];
        bf16x4 va = {(bf16_t)a.x, (bf16_t)a.y, (bf16_t)a.z, (bf16_t)a.w};
        bf16x4 vb = {(bf16_t)b.x, (bf16_t)b.y, (bf16_t)b.z, (bf16_t)b.w};
        bf16x4 vs = {(bf16_t)(a.x + b.x), (bf16_t)(a.y + b.y),
                     (bf16_t)(a.z + b.z), (bf16_t)(a.w + b.w)};
        Wih0R[t] = va; Whh0R[t] = vb; Wsum0R[t] = vs;
    } else if (t < 2097152) {
        const int i = t - 1048576;
        const int j = i >> 8, col = i & 255;
        const int g = j & 3, nn = j >> 2;
        const int src = (g * 1024 + nn) * 256 + col;
        const float4 a = Wih1[src];
        const float4 b = Whh1[src];
        bf16x4 va = {(bf16_t)a.x, (bf16_t)a.y, (bf16_t)a.z, (bf16_t)a.w};
        bf16x4 vb = {(bf16_t)b.x, (bf16_t)b.y, (bf16_t)b.z, (bf16_t)b.w};
        WcatR1[j * 512 + col]       = va;
        WcatR1[j * 512 + 256 + col] = vb;
    } else if (t < 2359296) {
        const int i = t - 2097152;
        const float4 a = Wlin[i];
        bf16x4 v = {(bf16_t)a.x, (bf16_t)a.y, (bf16_t)a.z, (bf16_t)a.w};
        Wlinb[i] = v;
    } else if (t < 2621440) {
        const int i = t - 2359296;            // 0..262143, 4 elems each
        const int b = i >> 8, n4 = i & 255;
        const float4 v = ((const float4*)z)[i];
        bf16x4 hv = {(bf16_t)v.x, (bf16_t)v.y, (bf16_t)v.z, (bf16_t)v.w};
        ((bf16x4*)zb)[i] = hv;
        *(bf16x4*)(X0 + (size_t)b * 2048 + 1024 + n4 * 4) = hv;   // h1(0) = z
        ((float4*)c0)[i] = v;
        ((float4*)c1)[i] = v;
    } else if (t < 2622464) {
        const int nn = t - 2621440;           // 0..1023 -> j = 4nn+g
        float4 b0, b1;
        float* p0 = (float*)&b0; float* p1 = (float*)&b1;
#pragma unroll
        for (int g = 0; g < 4; ++g) {
            p0[g] = bih0[g * 1024 + nn] + bhh0[g * 1024 + nn];
            p1[g] = bih1[g * 1024 + nn] + bhh1[g * 1024 + nn];
        }
        ((float4*)b0R)[nn] = b0;
        ((float4*)b1R)[nn] = b1;
    }
}

extern "C" void kernel_launch(void* const* d_in, const int* in_sizes, int n_in,
                              void* d_out, int out_size, void* d_ws, size_t ws_size,
                              hipStream_t stream)
{
    const float* z     = (const float*)d_in[0];
    const float* W_ih0 = (const float*)d_in[1];
    const float* W_hh0 = (const float*)d_in[2];
    const float* b_ih0 = (const float*)d_in[3];
    const float* b_hh0 = (const float*)d_in[4];
    const float* W_ih1 = (const float*)d_in[5];
    const float* W_hh1 = (const float*)d_in[6];
    const float* b_ih1 = (const float*)d_in[7];
    const float* b_hh1 = (const float*)d_in[8];
    const float* W_lin = (const float*)d_in[9];
    const float* b_lin = (const float*)d_in[10];
    float* out = (float*)d_out;

    char* ws = (char*)d_ws;
    const size_t MB = 1u << 20;
    bf16_t* WcatR1 = (bf16_t*)(ws);               // 16MB [4096][2048] = [Wih1R | Whh1R]
    bf16_t* Whh0R  = (bf16_t*)(ws + 16 * MB);     // 8MB  [4096][1024]
    bf16_t* Wih0R  = (bf16_t*)(ws + 24 * MB);     // 8MB
    bf16_t* Wsum0R = (bf16_t*)(ws + 32 * MB);     // 8MB
    bf16_t* Wlinb  = (bf16_t*)(ws + 40 * MB);     // 2MB
    bf16_t* zb     = (bf16_t*)(ws + 42 * MB);     // 2MB
    bf16_t* Xbuf   = (bf16_t*)(ws + 44 * MB);     // 8MB: X[2] each [1024][2048]
    float*  Gz0R   = (float*) (ws + 52 * MB);     // 16MB [1024][4096]
    bf16_t* stash  = (bf16_t*)(ws + 68 * MB);     // 8MB: 4 x [1024][1024]
    float*  c0     = (float*) (ws + 76 * MB);     // 4MB
    float*  c1     = (float*) (ws + 80 * MB);     // 4MB
    float*  bias0R = (float*) (ws + 84 * MB);     // 16KB
    float*  bias1R = (float*) (ws + 84 * MB + 16384);
    float*  Gz1R   = (float*) (ws + 88 * MB);     // 16MB [1024][4096]
    bf16_t* X[2] = {Xbuf, Xbuf + (size_t)(1u << 21)};

    prep_all<<<10244, 256, 0, stream>>>(
        z, (const float4*)W_ih0, (const float4*)W_hh0,
        (const float4*)W_ih1, (const float4*)W_hh1, (const float4*)W_lin,
        b_ih0, b_hh0, b_ih1, b_hh1,
        (bf16x4*)Wih0R, (bf16x4*)Whh0R, (bf16x4*)Wsum0R,
        (bf16x4*)WcatR1, (bf16x4*)Wlinb,
        zb, X[0], c0, c1, bias0R, bias1R);

    Job empty = {};

    // D1 (768 blocks, all K=1024):
    //   Gz0R = z@Wih0R^T + bias0R  ||  f00: h0(1)=cell0(z@Wsum0R^T + bias0R)
    //   ||  Gz1R = z@Whh1R^T + bias1R   (Whh1R = WcatR1 cols 1024.., ldb 2048)
    {
        Job gz = {};
        gz.A = zb; gz.lda = 1024; gz.B = Wih0R; gz.ldb = 1024; gz.K = 1024;
        gz.bias = bias0R; gz.C = Gz0R; gz.mode = 1;
        Job f00 = {};
        f00.A = zb; f00.lda = 1024; f00.B = Wsum0R; f00.ldb = 1024; f00.K = 1024;
        f00.bias = bias0R; f00.c = c0; f00.h1 = X[0]; f00.h1s = 2048; f00.mode = 0;
        Job gz1 = {};
        gz1.A = zb; gz1.lda = 1024; gz1.B = WcatR1 + 1024; gz1.ldb = 2048; gz1.K = 1024;
        gz1.bias = bias1R; gz1.C = Gz1R; gz1.mode = 1;
        fused_multi<<<768, 256, 0, stream>>>(gz, f00, gz1, 256, 512);
    }

    // D2..D5: combo(t) = f1(t) || f0(t+1) (t<3) || lin(t-1) (t>=1)
    for (int t = 0; t < 4; ++t) {
        const int p = t & 1;
        Job a0 = {};   // f1(t): writes h1(t+1)
        if (t == 0) {  // K=1024: h0(1)@Wih1R^T + Gz1R  (z-half precomputed)
            a0.A = X[0]; a0.lda = 2048; a0.B = WcatR1; a0.ldb = 2048; a0.K = 1024;
            a0.add = Gz1R; a0.bias = nullptr;
        } else {       // K=2048: [h0(t+1)|h1(t)] @ WcatR1^T + bias1R
            a0.A = X[p]; a0.lda = 2048; a0.B = WcatR1; a0.ldb = 2048; a0.K = 2048;
            a0.bias = bias1R;
        }
        a0.c = c1;
        a0.h1 = stash + (size_t)t * (1u << 20); a0.h1s = 1024;
        if (t < 3) { a0.h2 = X[p ^ 1] + 1024; a0.h2s = 2048; }
        a0.mode = 0;

        Job a1 = {};   // f0(t+1): K=1024, reads X[p] x-slot, writes X[p^1] x-slot
        if (t < 3) {
            a1.A = X[p]; a1.lda = 2048; a1.B = Whh0R; a1.ldb = 1024; a1.K = 1024;
            a1.add = Gz0R; a1.c = c0; a1.h1 = X[p ^ 1]; a1.h1s = 2048; a1.mode = 0;
        }

        Job lj = {};   // lin(t-1): out[:, t-1, :] = stash(t-1)@Wlinb^T + b_lin
        if (t >= 1) {
            lj.A = stash + (size_t)(t - 1) * (1u << 20); lj.lda = 1024;
            lj.B = Wlinb; lj.ldb = 1024; lj.K = 1024; lj.bias = b_lin;
            lj.C = out + (size_t)(t - 1) * 1024; lj.mode = 1;
        }

        if (t == 0)      fused_multi<<<512, 256, 0, stream>>>(a0, a1, empty, 256, 512);
        else if (t < 3)  fused_multi<<<576, 256, 0, stream>>>(a0, a1, lj, 256, 512);
        else             fused_multi<<<320, 256, 0, stream>>>(a0, lj, empty, 256, 320);
    }

    // D6: lin(3)
    {
        Job lj = {};
        lj.A = stash + (size_t)3 * (1u << 20); lj.lda = 1024;
        lj.B = Wlinb; lj.ldb = 1024; lj.K = 1024; lj.bias = b_lin;
        lj.C = out + (size_t)3 * 1024; lj.mode = 1;
        fused_multi<<<64, 256, 0, stream>>>(lj, empty, empty, 64, 64);
    }
}

// Round 15
// 212.297 us; speedup vs baseline: 1.1600x; 1.1600x over previous
//
#include <hip/hip_runtime.h>
#include <hip/hip_bf16.h>
#include <cstdint>
#include <cstddef>

// LSTM fused pipeline, round 15 = R13 (best, 215us) + T5 setprio around MFMA.
// Core: 128x128 tile, 512 thr / 8 waves (2x4), wave 64x32, BK=64,
// 2x32KB dbuf LDS (2 blocks/CU = 16 waves/CU), counted vmcnt(4) schedule
// (loads stay in flight across barriers; never drains to 0 in-loop),
// rule#21 both-sides swizzle (0 bank conflicts, verified R13).
// T5: s_setprio(1) entering the MFMA cluster, (0) after -- scheduler favors
// MFMA-entering waves over staging waves (role diversity exists here).
// Algorithmic: Wsum0 t=0 trick; Gz1R = z@Whh1^T+bias1 precomputed (D1);
// lin(t) folded into combo(t+1); 7 dispatches.

typedef __bf16 bf16_t;
typedef __bf16 bf16x8 __attribute__((ext_vector_type(8)));
typedef __bf16 bf16x4 __attribute__((ext_vector_type(4)));
typedef float f32x4 __attribute__((ext_vector_type(4)));

__device__ __forceinline__ void gload_lds16(const bf16_t* g, bf16_t* l) {
    __builtin_amdgcn_global_load_lds(
        (const __attribute__((address_space(1))) void*)g,
        (__attribute__((address_space(3))) void*)l,
        16, 0, 0);
}

__device__ __forceinline__ float sigmoid_f(float x) {
    return 1.f / (1.f + __expf(-x));
}
__device__ __forceinline__ float tanh_fast(float x) {
    const float t = __expf(2.f * x);
    return 1.f - 2.f / (t + 1.f);
}

// mode 0: GEMM + LSTM cell epilogue (gate-interleaved cols j=4n+g).
// mode 1: GEMM + bias -> f32 C (ldc fixed 4096).
struct Job {
    const bf16_t* A;       // [1024][lda]
    const bf16_t* B;       // [N][ldb], K<=ldb
    const float*  add;     // f32 [1024][4096] or null
    const float*  bias;    // f32 or null
    float*        c;       // f32 [1024][1024] cell state         (mode 0)
    bf16_t*       h1;      // h dest 1                            (mode 0)
    bf16_t*       h2;      // h dest 2 or null                    (mode 0)
    float*        C;       // f32 out, ldc=4096                   (mode 1)
    int lda, ldb, K, h1s, h2s, mode;
};

// All jobs: M=1024 (8 row-tiles of 128). block = 512 (8 waves, 2x4),
// wave = 64x32 = 4x2 frags. LDS: 2 bufs x (lsA 16KB | lsB 16KB).
__global__ __launch_bounds__(512, 4) void fused_multi(Job j0, Job j1, Job j2, int n0, int n01)
{
    __shared__ __align__(16) char smem[65536];
    float* gsm = (float*)smem;

    const int bid = blockIdx.x;
    Job ja; int local, n;
    if (bid < n0)        { ja = j0; local = bid;       n = n0; }
    else if (bid < n01)  { ja = j1; local = bid - n0;  n = n01 - n0; }
    else                 { ja = j2; local = bid - n01; n = (int)gridDim.x - n01; }

    // XCD-aware: bid%8 = XCD (job bases %8==0); x-major chunks per XCD so
    // same-B-panel tiles share an L2.
    const int q    = n >> 3;                          // n is a multiple of 8
    const int tile = (local & 7) * q + (local >> 3);
    const int bcol = (tile >> 3) * 128;
    const int brow = (tile & 7) * 128;

    const int tid  = threadIdx.x;
    const int lane = tid & 63;
    const int wave = tid >> 6;            // 0..7
    const int wm = (wave >> 2) * 64;
    const int wn = (wave & 3) * 32;

    const int srow = lane >> 3;                  // 0..7
    const int ssw  = ((lane & 7) ^ srow) * 8;    // pre-swizzled source col (rule #21)
    const int ch0  = wave * 2;
    const int nkt  = ja.K >> 6;

    const int fr  = lane & 15;
    const int g8  = (lane >> 4) * 8;
    const int rsw = (fr & 7) * 8;                // read-side swizzle XOR (elems)

    f32x4 acc[4][2] = {};

    auto stage = [&](int buf, int ktel) {        // 4 gload_lds per wave
        bf16_t* lsA = (bf16_t*)(smem + buf * 32768);
        bf16_t* lsB = (bf16_t*)(smem + buf * 32768 + 16384);
#pragma unroll
        for (int it = 0; it < 2; ++it) {
            const int ch = ch0 + it;             // 0..15
            const int row = ch * 8 + srow;       // 0..127
            gload_lds16(ja.A + (size_t)(brow + row) * ja.lda + ktel + ssw, &lsA[ch * 512]);
            gload_lds16(ja.B + (size_t)(bcol + row) * ja.ldb + ktel + ssw, &lsB[ch * 512]);
        }
    };

    stage(0, 0);

    for (int kt = 0; kt < nkt; ++kt) {
        const int buf = kt & 1;
        if (kt + 1 < nkt) {
            stage(buf ^ 1, (kt + 1) << 6);       // prefetch: 4 more in flight
            asm volatile("s_waitcnt vmcnt(4)" ::: "memory");   // wait stage(kt) only
        } else {
            asm volatile("s_waitcnt vmcnt(0)" ::: "memory");   // final drain
        }
        __builtin_amdgcn_sched_barrier(0);
        __builtin_amdgcn_s_barrier();            // all waves' stage(kt) landed
        __builtin_amdgcn_sched_barrier(0);

        const bf16_t* lsA = (const bf16_t*)(smem + buf * 32768);
        const bf16_t* lsB = (const bf16_t*)(smem + buf * 32768 + 16384);
        __builtin_amdgcn_s_setprio(1);           // T5: favor MFMA-entering waves
#pragma unroll
        for (int kk = 0; kk < 2; ++kk) {
            const int ko = (kk * 32 + g8) ^ rsw;
            bf16x8 af[4], bfv[2];
#pragma unroll
            for (int m = 0; m < 4; ++m)
                af[m] = *(const bf16x8*)&lsA[(wm + m * 16 + fr) * 64 + ko];
#pragma unroll
            for (int nn = 0; nn < 2; ++nn)
                bfv[nn] = *(const bf16x8*)&lsB[(wn + nn * 16 + fr) * 64 + ko];
#pragma unroll
            for (int m = 0; m < 4; ++m)
#pragma unroll
                for (int nn = 0; nn < 2; ++nn)
                    acc[m][nn] = __builtin_amdgcn_mfma_f32_16x16x32_bf16(af[m], bfv[nn], acc[m][nn], 0, 0, 0);
        }
        __builtin_amdgcn_s_setprio(0);
        __builtin_amdgcn_sched_barrier(0);
        __builtin_amdgcn_s_barrier();            // WAR: next iter's stage overwrites buf^1
    }

    // C/D layout: col = lane&15, row = (lane>>4)*4 + reg
    const int cr = (lane >> 4) * 4;
    const int cc = lane & 15;

    if (ja.mode == 1) {
#pragma unroll
        for (int nn = 0; nn < 2; ++nn) {
            const int col = bcol + wn + nn * 16 + cc;
            const float bv = ja.bias ? ja.bias[col] : 0.f;
#pragma unroll
            for (int m = 0; m < 4; ++m) {
                const int row0 = brow + wm + m * 16 + cr;
#pragma unroll
                for (int r = 0; r < 4; ++r)
                    ja.C[(size_t)(row0 + r) * 4096 + col] = acc[m][nn][r] + bv;
            }
        }
        return;
    }

    // mode 0: stage 128x128 f32 tile in 64KB LDS (2-way col swizzle), then cell
#pragma unroll
    for (int nn = 0; nn < 2; ++nn)
#pragma unroll
        for (int m = 0; m < 4; ++m)
#pragma unroll
            for (int r = 0; r < 4; ++r) {
                const int row = wm + m * 16 + cr + r;
                const int col = wn + nn * 16 + cc;
                gsm[row * 128 + (col ^ (((row >> 2) & 1) << 4))] = acc[m][nn][r];
            }
    __syncthreads();

    // cell: 128 rows x 32 n-quads = 4096 items, 8 per thread
#pragma unroll
    for (int p = 0; p < 8; ++p) {
        const int idx = p * 512 + tid;
        const int rl = idx >> 5;          // 0..127
        const int nn = idx & 31;          // 0..31
        float4 gv = *(const float4*)&gsm[rl * 128 + ((nn * 4) ^ (((rl >> 2) & 1) << 4))];
        const int grow = brow + rl;
        const int j0c = bcol + nn * 4;
        if (ja.add) {
            const float4 av = *(const float4*)&ja.add[(size_t)grow * 4096 + j0c];
            gv.x += av.x; gv.y += av.y; gv.z += av.z; gv.w += av.w;
        }
        if (ja.bias) {
            const float4 bv = *(const float4*)&ja.bias[j0c];
            gv.x += bv.x; gv.y += bv.y; gv.z += bv.z; gv.w += bv.w;
        }
        const int ng = j0c >> 2;          // global n
        const size_t ci = (size_t)grow * 1024 + ng;
        const float cn = sigmoid_f(gv.y) * ja.c[ci] + sigmoid_f(gv.x) * tanh_fast(gv.z);
        const float hh = sigmoid_f(gv.w) * tanh_fast(cn);
        ja.c[ci] = cn;
        const bf16_t hb = (bf16_t)hh;
        ja.h1[(size_t)grow * ja.h1s + ng] = hb;
        if (ja.h2) ja.h2[(size_t)grow * ja.h2s + ng] = hb;
    }
}

// ---- merged prep: all weight conversions + reorders + init in ONE dispatch ----
__global__ __launch_bounds__(256) void prep_all(
    const float* __restrict__ z,
    const float4* __restrict__ Wih0, const float4* __restrict__ Whh0,
    const float4* __restrict__ Wih1, const float4* __restrict__ Whh1,
    const float4* __restrict__ Wlin,
    const float* __restrict__ bih0, const float* __restrict__ bhh0,
    const float* __restrict__ bih1, const float* __restrict__ bhh1,
    bf16x4* __restrict__ Wih0R, bf16x4* __restrict__ Whh0R, bf16x4* __restrict__ Wsum0R,
    bf16x4* __restrict__ WcatR1, bf16x4* __restrict__ Wlinb,
    bf16_t* __restrict__ zb, bf16_t* __restrict__ X0,
    float* __restrict__ c0, float* __restrict__ c1,
    float* __restrict__ b0R, float* __restrict__ b1R)
{
    const int t = blockIdx.x * 256 + threadIdx.x;
    if (t < 1048576) {
        const int j = t >> 8, col = t & 255;
        const int g = j & 3, nn = j >> 2;
        const int src = (g * 1024 + nn) * 256 + col;
        const float4 a = Wih0[src];
        const float4 b = Whh0[src];
        bf16x4 va = {(bf16_t)a.x, (bf16_t)a.y, (bf16_t)a.z, (bf16_t)a.w};
        bf16x4 vb = {(bf16_t)b.x, (bf16_t)b.y, (bf16_t)b.z, (bf16_t)b.w};
        bf16x4 vs = {(bf16_t)(a.x + b.x), (bf16_t)(a.y + b.y),
                     (bf16_t)(a.z + b.z), (bf16_t)(a.w + b.w)};
        Wih0R[t] = va; Whh0R[t] = vb; Wsum0R[t] = vs;
    } else if (t < 2097152) {
        const int i = t - 1048576;
        const int j = i >> 8, col = i & 255;
        const int g = j & 3, nn = j >> 2;
        const int src = (g * 1024 + nn) * 256 + col;
        const float4 a = Wih1[src];
        const float4 b = Whh1[src];
        bf16x4 va = {(bf16_t)a.x, (bf16_t)a.y, (bf16_t)a.z, (bf16_t)a.w};
        bf16x4 vb = {(bf16_t)b.x, (bf16_t)b.y, (bf16_t)b.z, (bf16_t)b.w};
        WcatR1[j * 512 + col]       = va;
        WcatR1[j * 512 + 256 + col] = vb;
    } else if (t < 2359296) {
        const int i = t - 2097152;
        const float4 a = Wlin[i];
        bf16x4 v = {(bf16_t)a.x, (bf16_t)a.y, (bf16_t)a.z, (bf16_t)a.w};
        Wlinb[i] = v;
    } else if (t < 2621440) {
        const int i = t - 2359296;            // 0..262143, 4 elems each
        const int b = i >> 8, n4 = i & 255;
        const float4 v = ((const float4*)z)[i];
        bf16x4 hv = {(bf16_t)v.x, (bf16_t)v.y, (bf16_t)v.z, (bf16_t)v.w};
        ((bf16x4*)zb)[i] = hv;
        *(bf16x4*)(X0 + (size_t)b * 2048 + 1024 + n4 * 4) = hv;   // h1(0) = z
        ((float4*)c0)[i] = v;
        ((float4*)c1)[i] = v;
    } else if (t < 2622464) {
        const int nn = t - 2621440;           // 0..1023 -> j = 4nn+g
        float4 b0, b1;
        float* p0 = (float*)&b0; float* p1 = (float*)&b1;
#pragma unroll
        for (int g = 0; g < 4; ++g) {
            p0[g] = bih0[g * 1024 + nn] + bhh0[g * 1024 + nn];
            p1[g] = bih1[g * 1024 + nn] + bhh1[g * 1024 + nn];
        }
        ((float4*)b0R)[nn] = b0;
        ((float4*)b1R)[nn] = b1;
    }
}

extern "C" void kernel_launch(void* const* d_in, const int* in_sizes, int n_in,
                              void* d_out, int out_size, void* d_ws, size_t ws_size,
                              hipStream_t stream)
{
    const float* z     = (const float*)d_in[0];
    const float* W_ih0 = (const float*)d_in[1];
    const float* W_hh0 = (const float*)d_in[2];
    const float* b_ih0 = (const float*)d_in[3];
    const float* b_hh0 = (const float*)d_in[4];
    const float* W_ih1 = (const float*)d_in[5];
    const float* W_hh1 = (const float*)d_in[6];
    const float* b_ih1 = (const float*)d_in[7];
    const float* b_hh1 = (const float*)d_in[8];
    const float* W_lin = (const float*)d_in[9];
    const float* b_lin = (const float*)d_in[10];
    float* out = (float*)d_out;

    char* ws = (char*)d_ws;
    const size_t MB = 1u << 20;
    bf16_t* WcatR1 = (bf16_t*)(ws);               // 16MB [4096][2048] = [Wih1R | Whh1R]
    bf16_t* Whh0R  = (bf16_t*)(ws + 16 * MB);     // 8MB  [4096][1024]
    bf16_t* Wih0R  = (bf16_t*)(ws + 24 * MB);     // 8MB
    bf16_t* Wsum0R = (bf16_t*)(ws + 32 * MB);     // 8MB
    bf16_t* Wlinb  = (bf16_t*)(ws + 40 * MB);     // 2MB
    bf16_t* zb     = (bf16_t*)(ws + 42 * MB);     // 2MB
    bf16_t* Xbuf   = (bf16_t*)(ws + 44 * MB);     // 8MB: X[2] each [1024][2048]
    float*  Gz0R   = (float*) (ws + 52 * MB);     // 16MB [1024][4096]
    bf16_t* stash  = (bf16_t*)(ws + 68 * MB);     // 8MB: 4 x [1024][1024]
    float*  c0     = (float*) (ws + 76 * MB);     // 4MB
    float*  c1     = (float*) (ws + 80 * MB);     // 4MB
    float*  bias0R = (float*) (ws + 84 * MB);     // 16KB
    float*  bias1R = (float*) (ws + 84 * MB + 16384);
    float*  Gz1R   = (float*) (ws + 88 * MB);     // 16MB [1024][4096]
    bf16_t* X[2] = {Xbuf, Xbuf + (size_t)(1u << 21)};

    prep_all<<<10244, 256, 0, stream>>>(
        z, (const float4*)W_ih0, (const float4*)W_hh0,
        (const float4*)W_ih1, (const float4*)W_hh1, (const float4*)W_lin,
        b_ih0, b_hh0, b_ih1, b_hh1,
        (bf16x4*)Wih0R, (bf16x4*)Whh0R, (bf16x4*)Wsum0R,
        (bf16x4*)WcatR1, (bf16x4*)Wlinb,
        zb, X[0], c0, c1, bias0R, bias1R);

    Job empty = {};

    // D1 (768 blocks, all K=1024):
    //   Gz0R = z@Wih0R^T + bias0R  ||  f00: h0(1)=cell0(z@Wsum0R^T + bias0R)
    //   ||  Gz1R = z@Whh1R^T + bias1R   (Whh1R = WcatR1 cols 1024.., ldb 2048)
    {
        Job gz = {};
        gz.A = zb; gz.lda = 1024; gz.B = Wih0R; gz.ldb = 1024; gz.K = 1024;
        gz.bias = bias0R; gz.C = Gz0R; gz.mode = 1;
        Job f00 = {};
        f00.A = zb; f00.lda = 1024; f00.B = Wsum0R; f00.ldb = 1024; f00.K = 1024;
        f00.bias = bias0R; f00.c = c0; f00.h1 = X[0]; f00.h1s = 2048; f00.mode = 0;
        Job gz1 = {};
        gz1.A = zb; gz1.lda = 1024; gz1.B = WcatR1 + 1024; gz1.ldb = 2048; gz1.K = 1024;
        gz1.bias = bias1R; gz1.C = Gz1R; gz1.mode = 1;
        fused_multi<<<768, 512, 0, stream>>>(gz, f00, gz1, 256, 512);
    }

    // D2..D5: combo(t) = f1(t) || f0(t+1) (t<3) || lin(t-1) (t>=1)
    for (int t = 0; t < 4; ++t) {
        const int p = t & 1;
        Job a0 = {};   // f1(t): writes h1(t+1)
        if (t == 0) {  // K=1024: h0(1)@Wih1R^T + Gz1R  (z-half precomputed)
            a0.A = X[0]; a0.lda = 2048; a0.B = WcatR1; a0.ldb = 2048; a0.K = 1024;
            a0.add = Gz1R; a0.bias = nullptr;
        } else {       // K=2048: [h0(t+1)|h1(t)] @ WcatR1^T + bias1R
            a0.A = X[p]; a0.lda = 2048; a0.B = WcatR1; a0.ldb = 2048; a0.K = 2048;
            a0.bias = bias1R;
        }
        a0.c = c1;
        a0.h1 = stash + (size_t)t * (1u << 20); a0.h1s = 1024;
        if (t < 3) { a0.h2 = X[p ^ 1] + 1024; a0.h2s = 2048; }
        a0.mode = 0;

        Job a1 = {};   // f0(t+1): K=1024, reads X[p] x-slot, writes X[p^1] x-slot
        if (t < 3) {
            a1.A = X[p]; a1.lda = 2048; a1.B = Whh0R; a1.ldb = 1024; a1.K = 1024;
            a1.add = Gz0R; a1.c = c0; a1.h1 = X[p ^ 1]; a1.h1s = 2048; a1.mode = 0;
        }

        Job lj = {};   // lin(t-1): out[:, t-1, :] = stash(t-1)@Wlinb^T + b_lin
        if (t >= 1) {
            lj.A = stash + (size_t)(t - 1) * (1u << 20); lj.lda = 1024;
            lj.B = Wlinb; lj.ldb = 1024; lj.K = 1024; lj.bias = b_lin;
            lj.C = out + (size_t)(t - 1) * 1024; lj.mode = 1;
        }

        if (t == 0)      fused_multi<<<512, 512, 0, stream>>>(a0, a1, empty, 256, 512);
        else if (t < 3)  fused_multi<<<576, 512, 0, stream>>>(a0, a1, lj, 256, 512);
        else             fused_multi<<<320, 512, 0, stream>>>(a0, lj, empty, 256, 320);
    }

    // D6: lin(3)
    {
        Job lj = {};
        lj.A = stash + (size_t)3 * (1u << 20); lj.lda = 1024;
        lj.B = Wlinb; lj.ldb = 1024; lj.K = 1024; lj.bias = b_lin;
        lj.C = out + (size_t)3 * 1024; lj.mode = 1;
        fused_multi<<<64, 512, 0, stream>>>(lj, empty, empty, 64, 64);
    }
}